// Round 1
// baseline (2204.847 us; speedup 1.0000x reference)
//
#include <hip/hip_runtime.h>

#define SEQ   4096
#define NH    16
#define HD    80
#define DIM   1280
#define N3    3840
#define SCALE 0.11180339887498949f   // 80^-0.5

// ---------------------------------------------------------------------------
// GEMM: C = A @ W^T + bias.  A[M][1280], W[N][1280].
// 128x128 tile, 256 threads, 8x8 per thread, K-step 16.
// SCATTER=true: N=3840, scatter into qkv ws layout [which][h][s][d]
// SCATTER=false: N=1280, plain row-major C[m][n]
// ---------------------------------------------------------------------------
template <bool SCATTER>
__global__ __launch_bounds__(256)
void gemm_kernel(const float* __restrict__ A, const float* __restrict__ W,
                 const float* __restrict__ bias, float* __restrict__ C)
{
    __shared__ float As[16][132];
    __shared__ float Bs[16][132];
    const int tid = threadIdx.x;
    const int bm = blockIdx.y * 128;
    const int bn = blockIdx.x * 128;
    const int tx = tid & 15;        // n-dir
    const int ty = tid >> 4;        // m-dir
    const int lr = tid >> 2;        // 0..63
    const int lc = (tid & 3) << 2;  // 0,4,8,12

    float acc[8][8];
#pragma unroll
    for (int i = 0; i < 8; ++i)
#pragma unroll
        for (int j = 0; j < 8; ++j) acc[i][j] = 0.f;

    for (int k0 = 0; k0 < DIM; k0 += 16) {
        float4 a0 = *(const float4*)&A[(size_t)(bm + lr) * DIM + k0 + lc];
        float4 a1 = *(const float4*)&A[(size_t)(bm + lr + 64) * DIM + k0 + lc];
        float4 b0 = *(const float4*)&W[(size_t)(bn + lr) * DIM + k0 + lc];
        float4 b1 = *(const float4*)&W[(size_t)(bn + lr + 64) * DIM + k0 + lc];
        __syncthreads();
        As[lc + 0][lr] = a0.x; As[lc + 1][lr] = a0.y;
        As[lc + 2][lr] = a0.z; As[lc + 3][lr] = a0.w;
        As[lc + 0][lr + 64] = a1.x; As[lc + 1][lr + 64] = a1.y;
        As[lc + 2][lr + 64] = a1.z; As[lc + 3][lr + 64] = a1.w;
        Bs[lc + 0][lr] = b0.x; Bs[lc + 1][lr] = b0.y;
        Bs[lc + 2][lr] = b0.z; Bs[lc + 3][lr] = b0.w;
        Bs[lc + 0][lr + 64] = b1.x; Bs[lc + 1][lr + 64] = b1.y;
        Bs[lc + 2][lr + 64] = b1.z; Bs[lc + 3][lr + 64] = b1.w;
        __syncthreads();
#pragma unroll
        for (int kk = 0; kk < 16; ++kk) {
            float4 av0 = *(const float4*)&As[kk][ty * 8];
            float4 av1 = *(const float4*)&As[kk][ty * 8 + 4];
            float4 bv0 = *(const float4*)&Bs[kk][tx * 8];
            float4 bv1 = *(const float4*)&Bs[kk][tx * 8 + 4];
            float a_[8] = {av0.x, av0.y, av0.z, av0.w, av1.x, av1.y, av1.z, av1.w};
            float b_[8] = {bv0.x, bv0.y, bv0.z, bv0.w, bv1.x, bv1.y, bv1.z, bv1.w};
#pragma unroll
            for (int i = 0; i < 8; ++i)
#pragma unroll
                for (int j = 0; j < 8; ++j)
                    acc[i][j] = fmaf(a_[i], b_[j], acc[i][j]);
        }
    }

#pragma unroll
    for (int i = 0; i < 8; ++i) {
        const int m = bm + ty * 8 + i;
#pragma unroll
        for (int j = 0; j < 8; ++j) {
            const int n = bn + tx * 8 + j;
            const float v = acc[i][j] + bias[n];
            if (SCATTER) {
                const int which = n / DIM;
                const int rem = n - which * DIM;
                const int h = rem / HD;
                const int d = rem - h * HD;
                C[((size_t)(which * NH + h) * SEQ + m) * HD + d] = v;
            } else {
                C[(size_t)m * DIM + n] = v;
            }
        }
    }
}

// ---------------------------------------------------------------------------
// RoPE in-place on q,k (which=0,1). Folds softmax scaling into q.
// qkv layout: [which][h][s][d]
// ---------------------------------------------------------------------------
__global__ __launch_bounds__(256)
void rope_kernel(float* __restrict__ qkv, const float* __restrict__ cos_t,
                 const float* __restrict__ sin_t)
{
    const int idx = blockIdx.x * 256 + threadIdx.x; // over 2*NH*SEQ*40
    if (idx >= 2 * NH * SEQ * 40) return;
    const int d = idx % 40;
    const int s = (idx / 40) % SEQ;
    const int h = (idx / (40 * SEQ)) % NH;
    const int which = idx / (40 * SEQ * NH);
    float* base = qkv + ((size_t)(which * NH + h) * SEQ + s) * HD;
    const float x0 = base[d];
    const float x1 = base[d + 40];
    const float c0 = cos_t[s * HD + d];
    const float c1 = cos_t[s * HD + d + 40];
    const float s0 = sin_t[s * HD + d];
    const float s1 = sin_t[s * HD + d + 40];
    const float sc = (which == 0) ? SCALE : 1.0f;
    base[d]      = (x0 * c0 - x1 * s0) * sc;
    base[d + 40] = (x1 * c1 + x0 * s1) * sc;
}

// ---------------------------------------------------------------------------
// Flash attention fp32. One block = (head, 64-row q tile). 256 threads.
// Qst/Kst transposed [d][row] so inner-loop b128 reads are lane-contiguous.
// Pt transposed [k][q] so PV p-reads are b128, conflict-free.
// ---------------------------------------------------------------------------
__global__ __launch_bounds__(256)
void attn_kernel(const float* __restrict__ q, const float* __restrict__ k,
                 const float* __restrict__ v, float* __restrict__ o_out)
{
    __shared__ float Qst[HD][64];
    __shared__ float Kst[HD][64];
    __shared__ float Vs[64][84];
    __shared__ float Pt[64][68];
    __shared__ float mS[64], lS[64], aS[64];

    const int tid = threadIdx.x;
    const int h = blockIdx.y;
    const int qb = blockIdx.x * 64;
    const float* qh = q + (size_t)h * SEQ * HD;
    const float* kh = k + (size_t)h * SEQ * HD;
    const float* vh = v + (size_t)h * SEQ * HD;

    const int tx = tid & 15;   // 4 q-rows: 4tx..4tx+3
    const int ty = tid >> 4;   // S: 4 k-cols; PV: 5 dims

    // stage Q transposed (rows qb..qb+63)
#pragma unroll
    for (int ii = 0; ii < 5; ++ii) {
        const int id = tid + 256 * ii;      // 0..1279
        const int row = id / 20;
        const int c4 = (id % 20) * 4;
        float4 qv = *(const float4*)&qh[(size_t)(qb + row) * HD + c4];
        Qst[c4 + 0][row] = qv.x; Qst[c4 + 1][row] = qv.y;
        Qst[c4 + 2][row] = qv.z; Qst[c4 + 3][row] = qv.w;
    }
    if (tid < 64) { mS[tid] = -1e30f; lS[tid] = 0.f; }

    float o[4][5];
#pragma unroll
    for (int i = 0; i < 4; ++i)
#pragma unroll
        for (int j = 0; j < 5; ++j) o[i][j] = 0.f;

    for (int kb = 0; kb < SEQ; kb += 64) {
        __syncthreads();  // prev PV done; Q stage visible on first iter
        // stage K transposed + V natural
#pragma unroll
        for (int ii = 0; ii < 5; ++ii) {
            const int id = tid + 256 * ii;
            const int row = id / 20;
            const int c4 = (id % 20) * 4;
            float4 kv = *(const float4*)&kh[(size_t)(kb + row) * HD + c4];
            Kst[c4 + 0][row] = kv.x; Kst[c4 + 1][row] = kv.y;
            Kst[c4 + 2][row] = kv.z; Kst[c4 + 3][row] = kv.w;
            float4 vv = *(const float4*)&vh[(size_t)(kb + row) * HD + c4];
            *(float4*)&Vs[row][c4] = vv;
        }
        __syncthreads();

        // S[4tx+i][4ty+j] = q . k  (scaling already folded into q)
        float s_[4][4];
#pragma unroll
        for (int i = 0; i < 4; ++i)
#pragma unroll
            for (int j = 0; j < 4; ++j) s_[i][j] = 0.f;
        for (int d = 0; d < HD; ++d) {
            float4 qv = *(const float4*)&Qst[d][tx * 4];
            float4 kv = *(const float4*)&Kst[d][ty * 4];
            const float qa[4] = {qv.x, qv.y, qv.z, qv.w};
            const float ka[4] = {kv.x, kv.y, kv.z, kv.w};
#pragma unroll
            for (int i = 0; i < 4; ++i)
#pragma unroll
                for (int j = 0; j < 4; ++j)
                    s_[i][j] = fmaf(qa[i], ka[j], s_[i][j]);
        }
        // write transposed: Pt[col][row]
#pragma unroll
        for (int j = 0; j < 4; ++j) {
            float4 w;
            w.x = s_[0][j]; w.y = s_[1][j]; w.z = s_[2][j]; w.w = s_[3][j];
            *(float4*)&Pt[ty * 4 + j][tx * 4] = w;
        }
        __syncthreads();

        // online softmax: thread -> row r = tid>>2, 16 cols
        {
            const int r = tid >> 2;
            const int c0 = (tid & 3) * 16;
            float vals[16];
            float mx = -1e30f;
#pragma unroll
            for (int c = 0; c < 16; ++c) {
                vals[c] = Pt[c0 + c][r];
                mx = fmaxf(mx, vals[c]);
            }
            mx = fmaxf(mx, __shfl_xor(mx, 1));
            mx = fmaxf(mx, __shfl_xor(mx, 2));
            const float mold = mS[r];
            const float mnew = fmaxf(mold, mx);
            float sum = 0.f;
#pragma unroll
            for (int c = 0; c < 16; ++c) {
                const float p = __expf(vals[c] - mnew);
                Pt[c0 + c][r] = p;
                sum += p;
            }
            sum += __shfl_xor(sum, 1);
            sum += __shfl_xor(sum, 2);
            if ((tid & 3) == 0) {
                const float alpha = __expf(mold - mnew);
                mS[r] = mnew;
                lS[r] = lS[r] * alpha + sum;
                aS[r] = alpha;
            }
        }
        __syncthreads();

        // PV: o[rows 4tx+i][dims 5ty+j]
        float al[4];
#pragma unroll
        for (int i = 0; i < 4; ++i) al[i] = aS[tx * 4 + i];
#pragma unroll
        for (int i = 0; i < 4; ++i)
#pragma unroll
            for (int j = 0; j < 5; ++j) o[i][j] *= al[i];
        for (int kk = 0; kk < 64; ++kk) {
            float4 p4 = *(const float4*)&Pt[kk][tx * 4];
            const float pv[4] = {p4.x, p4.y, p4.z, p4.w};
#pragma unroll
            for (int j = 0; j < 5; ++j) {
                const float vv = Vs[kk][ty * 5 + j];
#pragma unroll
                for (int i = 0; i < 4; ++i)
                    o[i][j] = fmaf(pv[i], vv, o[i][j]);
            }
        }
    }

    float inv[4];
#pragma unroll
    for (int i = 0; i < 4; ++i) inv[i] = 1.0f / lS[tx * 4 + i];
#pragma unroll
    for (int i = 0; i < 4; ++i)
#pragma unroll
        for (int j = 0; j < 5; ++j)
            o_out[(size_t)(qb + tx * 4 + i) * DIM + h * HD + ty * 5 + j] =
                o[i][j] * inv[i];
}

// ---------------------------------------------------------------------------
extern "C" void kernel_launch(void* const* d_in, const int* in_sizes, int n_in,
                              void* d_out, int out_size, void* d_ws, size_t ws_size,
                              hipStream_t stream)
{
    const float* hidden = (const float*)d_in[0];
    // d_in[1] = cu_seqlens: unused by the reference
    const float* cos_t  = (const float*)d_in[2];
    const float* sin_t  = (const float*)d_in[3];
    const float* qkv_w  = (const float*)d_in[4];
    const float* qkv_b  = (const float*)d_in[5];
    const float* proj_w = (const float*)d_in[6];
    const float* proj_b = (const float*)d_in[7];
    float* out = (float*)d_out;

    float* ws   = (float*)d_ws;
    float* qkv  = ws;                                  // [3][NH][SEQ][HD]
    float* attn = ws + (size_t)3 * NH * SEQ * HD;      // [SEQ][DIM]

    // QKV = hidden @ qkv_w^T + qkv_b, scattered to [which][h][s][d]
    gemm_kernel<true><<<dim3(N3 / 128, SEQ / 128), 256, 0, stream>>>(
        hidden, qkv_w, qkv_b, qkv);

    // RoPE on q,k (+ fold 80^-0.5 into q)
    rope_kernel<<<(2 * NH * SEQ * 40 + 255) / 256, 256, 0, stream>>>(
        qkv, cos_t, sin_t);

    // flash attention -> attn [SEQ][DIM]
    attn_kernel<<<dim3(SEQ / 64, NH), 256, 0, stream>>>(
        qkv, qkv + (size_t)NH * SEQ * HD, qkv + (size_t)2 * NH * SEQ * HD, attn);

    // out = attn @ proj_w^T + proj_b
    gemm_kernel<false><<<dim3(DIM / 128, SEQ / 128), 256, 0, stream>>>(
        attn, proj_w, proj_b, out);
}

// Round 2
// 1001.222 us; speedup vs baseline: 2.2022x; 2.2022x over previous
//
#include <hip/hip_runtime.h>

#define SEQ   4096
#define NH    16
#define HD    80
#define DIM   1280
#define N3    3840
#define SCALE 0.11180339887498949f   // 80^-0.5

typedef __bf16 bf16x8 __attribute__((ext_vector_type(8)));
typedef float  f32x4  __attribute__((ext_vector_type(4)));

#define MFMA16(A,B,C) __builtin_amdgcn_mfma_f32_16x16x32_bf16(A,B,C,0,0,0)

static __device__ __forceinline__ unsigned short f2bf(float x){
    unsigned int u = __builtin_bit_cast(unsigned int, x);
    u = (u + 0x7FFFu + ((u >> 16) & 1u)) >> 16;   // RTNE, finite inputs
    return (unsigned short)u;
}
static __device__ __forceinline__ float bf2f(unsigned short h){
    return __builtin_bit_cast(float, ((unsigned int)h) << 16);
}
static __device__ __forceinline__ int packp(float a, float b){
    return (int)f2bf(a) | ((int)f2bf(b) << 16);
}

// ---------------------------------------------------------------------------
// fp32 GEMM: C = A @ W^T + bias (unchanged from R0)
// ---------------------------------------------------------------------------
template <bool SCATTER>
__global__ __launch_bounds__(256)
void gemm_kernel(const float* __restrict__ A, const float* __restrict__ W,
                 const float* __restrict__ bias, float* __restrict__ C)
{
    __shared__ float As[16][132];
    __shared__ float Bs[16][132];
    const int tid = threadIdx.x;
    const int bm = blockIdx.y * 128;
    const int bn = blockIdx.x * 128;
    const int tx = tid & 15;
    const int ty = tid >> 4;
    const int lr = tid >> 2;
    const int lc = (tid & 3) << 2;

    float acc[8][8];
#pragma unroll
    for (int i = 0; i < 8; ++i)
#pragma unroll
        for (int j = 0; j < 8; ++j) acc[i][j] = 0.f;

    for (int k0 = 0; k0 < DIM; k0 += 16) {
        float4 a0 = *(const float4*)&A[(size_t)(bm + lr) * DIM + k0 + lc];
        float4 a1 = *(const float4*)&A[(size_t)(bm + lr + 64) * DIM + k0 + lc];
        float4 b0 = *(const float4*)&W[(size_t)(bn + lr) * DIM + k0 + lc];
        float4 b1 = *(const float4*)&W[(size_t)(bn + lr + 64) * DIM + k0 + lc];
        __syncthreads();
        As[lc + 0][lr] = a0.x; As[lc + 1][lr] = a0.y;
        As[lc + 2][lr] = a0.z; As[lc + 3][lr] = a0.w;
        As[lc + 0][lr + 64] = a1.x; As[lc + 1][lr + 64] = a1.y;
        As[lc + 2][lr + 64] = a1.z; As[lc + 3][lr + 64] = a1.w;
        Bs[lc + 0][lr] = b0.x; Bs[lc + 1][lr] = b0.y;
        Bs[lc + 2][lr] = b0.z; Bs[lc + 3][lr] = b0.w;
        Bs[lc + 0][lr + 64] = b1.x; Bs[lc + 1][lr + 64] = b1.y;
        Bs[lc + 2][lr + 64] = b1.z; Bs[lc + 3][lr + 64] = b1.w;
        __syncthreads();
#pragma unroll
        for (int kk = 0; kk < 16; ++kk) {
            float4 av0 = *(const float4*)&As[kk][ty * 8];
            float4 av1 = *(const float4*)&As[kk][ty * 8 + 4];
            float4 bv0 = *(const float4*)&Bs[kk][tx * 8];
            float4 bv1 = *(const float4*)&Bs[kk][tx * 8 + 4];
            float a_[8] = {av0.x, av0.y, av0.z, av0.w, av1.x, av1.y, av1.z, av1.w};
            float b_[8] = {bv0.x, bv0.y, bv0.z, bv0.w, bv1.x, bv1.y, bv1.z, bv1.w};
#pragma unroll
            for (int i = 0; i < 8; ++i)
#pragma unroll
                for (int j = 0; j < 8; ++j)
                    acc[i][j] = fmaf(a_[i], b_[j], acc[i][j]);
        }
    }

#pragma unroll
    for (int i = 0; i < 8; ++i) {
        const int m = bm + ty * 8 + i;
#pragma unroll
        for (int j = 0; j < 8; ++j) {
            const int n = bn + tx * 8 + j;
            const float v = acc[i][j] + bias[n];
            if (SCATTER) {
                const int which = n / DIM;
                const int rem = n - which * DIM;
                const int hh = rem / HD;
                const int d = rem - hh * HD;
                C[((size_t)(which * NH + hh) * SEQ + m) * HD + d] = v;
            } else {
                C[(size_t)m * DIM + n] = v;
            }
        }
    }
}

// ---------------------------------------------------------------------------
// RoPE in-place on q,k; folds 80^-0.5 into q. (unchanged from R0)
// ---------------------------------------------------------------------------
__global__ __launch_bounds__(256)
void rope_kernel(float* __restrict__ qkv, const float* __restrict__ cos_t,
                 const float* __restrict__ sin_t)
{
    const int idx = blockIdx.x * 256 + threadIdx.x;
    if (idx >= 2 * NH * SEQ * 40) return;
    const int d = idx % 40;
    const int s = (idx / 40) % SEQ;
    const int h = (idx / (40 * SEQ)) % NH;
    const int which = idx / (40 * SEQ * NH);
    float* base = qkv + ((size_t)(which * NH + h) * SEQ + s) * HD;
    const float x0 = base[d];
    const float x1 = base[d + 40];
    const float c0 = cos_t[s * HD + d];
    const float c1 = cos_t[s * HD + d + 40];
    const float s0 = sin_t[s * HD + d];
    const float s1 = sin_t[s * HD + d + 40];
    const float sc = (which == 0) ? SCALE : 1.0f;
    base[d]      = (x0 * c0 - x1 * s0) * sc;
    base[d + 40] = (x1 * c1 + x0 * s1) * sc;
}

// ---------------------------------------------------------------------------
// V transpose + bf16 convert: v[h][s][d] fp32 -> vt[h][d][s] bf16
// ---------------------------------------------------------------------------
__global__ __launch_bounds__(256)
void vtrans_kernel(const float* __restrict__ v, unsigned short* __restrict__ vt)
{
    __shared__ float tile[64][84];
    const int tid = threadIdx.x;
    const int h = blockIdx.y;
    const int s0 = blockIdx.x * 64;
    const float* vh = v + (size_t)h * SEQ * HD;
#pragma unroll
    for (int ii = 0; ii < 5; ++ii) {
        const int id = tid + 256 * ii;
        const int r = id / 20, c4 = (id % 20) * 4;
        *(float4*)&tile[r][c4] = *(const float4*)(vh + (size_t)(s0 + r) * HD + c4);
    }
    __syncthreads();
#pragma unroll
    for (int ii = 0; ii < 5; ++ii) {
        const int id = tid + 256 * ii;
        const int d = id >> 4, c = (id & 15) * 4;
        const unsigned int u0 = f2bf(tile[c + 0][d]);
        const unsigned int u1 = f2bf(tile[c + 1][d]);
        const unsigned int u2 = f2bf(tile[c + 2][d]);
        const unsigned int u3 = f2bf(tile[c + 3][d]);
        uint2 w; w.x = u0 | (u1 << 16); w.y = u2 | (u3 << 16);
        *(uint2*)(vt + ((size_t)h * HD + d) * SEQ + s0 + c) = w;
    }
}

// ---------------------------------------------------------------------------
// MFMA flash attention.  Block = (head, 128 q rows), 4 waves * 32 q rows.
// Swapped QK^T:  St = mfma(A=K_tile, B=Q_frags)  ->  St[kv][q], q = lane&15.
// QK uses bf16 hi/lo 3-term split; PV uses single-bf16 P and V.
// K staged fp32->hi/lo in LDS (stride 104, 16B aligned, 2-way banks = free).
// V pre-transposed bf16 (vtrans) -> LDS stride 72, conflict-free b128 reads.
// P redistributed to PV A-fragments in-register via 8 shfls/frag.
// ---------------------------------------------------------------------------
__global__ __launch_bounds__(256, 2)
void attn_mfma(const float* __restrict__ q, const float* __restrict__ kk,
               const unsigned short* __restrict__ vt, float* __restrict__ o_out)
{
    __shared__ unsigned short Khi[64][104];
    __shared__ unsigned short Klo[64][104];
    __shared__ unsigned short Vt[80][72];

    const int tid = threadIdx.x;
    const int wq = tid >> 6;
    const int lane = tid & 63;
    const int lq = lane & 15;
    const int g = lane >> 4;
    const int h = blockIdx.y;
    const int qb = blockIdx.x * 128;

    const float* qh = q + (size_t)h * SEQ * HD;
    const float* kh = kk + (size_t)h * SEQ * HD;
    const unsigned short* vth = vt + (size_t)h * HD * SEQ;

    // zero the K pad columns [80,104) once; staging never overwrites them
    for (int i = tid; i < 64 * 24; i += 256) {
        const int r = i / 24, c = 80 + i % 24;
        Khi[r][c] = 0; Klo[r][c] = 0;
    }

    // ---- Q fragments (B operand): [nf][kstep], hi + lo ----
    bf16x8 qhiF[2][3], qloF[2][3];
#pragma unroll
    for (int nf = 0; nf < 2; ++nf) {
        const int qr = qb + wq * 32 + nf * 16 + lq;
        const float* qp = qh + (size_t)qr * HD;
#pragma unroll
        for (int ks = 0; ks < 3; ++ks) {
            const int d0 = ks * 32 + g * 8;
            union { unsigned short u[8]; bf16x8 v; } uh, ul;
            if (d0 < 80) {
                float4 x0 = *(const float4*)(qp + d0);
                float4 x1 = *(const float4*)(qp + d0 + 4);
                float xs[8] = {x0.x, x0.y, x0.z, x0.w, x1.x, x1.y, x1.z, x1.w};
#pragma unroll
                for (int i = 0; i < 8; ++i) {
                    const unsigned short hb = f2bf(xs[i]);
                    uh.u[i] = hb;
                    ul.u[i] = f2bf(xs[i] - bf2f(hb));
                }
            } else {
#pragma unroll
                for (int i = 0; i < 8; ++i) { uh.u[i] = 0; ul.u[i] = 0; }
            }
            qhiF[nf][ks] = uh.v; qloF[nf][ks] = ul.v;
        }
    }

    f32x4 o[2][5];
#pragma unroll
    for (int a = 0; a < 2; ++a)
#pragma unroll
        for (int b = 0; b < 5; ++b) o[a][b] = (f32x4)0.f;
    float mrow[2] = {-1e30f, -1e30f};
    float lrow[2] = {0.f, 0.f};

    for (int kb = 0; kb < SEQ; kb += 64) {
        // ---- issue staging loads (overlap prev iteration's tail) ----
        float4 kld[5]; uint2 vld[5];
        int kr_[5], kc_[5], vd_[5], vc_[5];
#pragma unroll
        for (int ii = 0; ii < 5; ++ii) {
            const int id = tid + 256 * ii;
            kr_[ii] = id / 20; kc_[ii] = (id % 20) * 4;
            kld[ii] = *(const float4*)(kh + (size_t)(kb + kr_[ii]) * HD + kc_[ii]);
        }
#pragma unroll
        for (int ii = 0; ii < 5; ++ii) {
            const int id = tid + 256 * ii;
            vd_[ii] = id >> 4; vc_[ii] = (id & 15) * 4;
            vld[ii] = *(const uint2*)(vth + (size_t)vd_[ii] * SEQ + kb + vc_[ii]);
        }
        __syncthreads();   // prev iteration's LDS reads complete
#pragma unroll
        for (int ii = 0; ii < 5; ++ii) {
            float xs[4] = {kld[ii].x, kld[ii].y, kld[ii].z, kld[ii].w};
            unsigned int hs[4], ls[4];
#pragma unroll
            for (int j = 0; j < 4; ++j) {
                hs[j] = f2bf(xs[j]);
                ls[j] = f2bf(xs[j] - bf2f((unsigned short)hs[j]));
            }
            uint2 wh, wl;
            wh.x = hs[0] | (hs[1] << 16); wh.y = hs[2] | (hs[3] << 16);
            wl.x = ls[0] | (ls[1] << 16); wl.y = ls[2] | (ls[3] << 16);
            *(uint2*)&Khi[kr_[ii]][kc_[ii]] = wh;
            *(uint2*)&Klo[kr_[ii]][kc_[ii]] = wl;
        }
#pragma unroll
        for (int ii = 0; ii < 5; ++ii)
            *(uint2*)&Vt[vd_[ii]][vc_[ii]] = vld[ii];
        __syncthreads();   // tiles ready

        // ---- QK^T (swapped): St[kv][q], 3-term hi/lo split ----
        f32x4 s[4][2];
#pragma unroll
        for (int mf = 0; mf < 4; ++mf)
#pragma unroll
            for (int nf = 0; nf < 2; ++nf) s[mf][nf] = (f32x4)0.f;
#pragma unroll
        for (int ks = 0; ks < 3; ++ks) {
#pragma unroll
            for (int mf = 0; mf < 4; ++mf) {
                bf16x8 ah = *(const bf16x8*)&Khi[mf * 16 + lq][ks * 32 + g * 8];
                bf16x8 al = *(const bf16x8*)&Klo[mf * 16 + lq][ks * 32 + g * 8];
#pragma unroll
                for (int nf = 0; nf < 2; ++nf) {
                    s[mf][nf] = MFMA16(ah, qhiF[nf][ks], s[mf][nf]);
                    s[mf][nf] = MFMA16(ah, qloF[nf][ks], s[mf][nf]);
                    s[mf][nf] = MFMA16(al, qhiF[nf][ks], s[mf][nf]);
                }
            }
        }

        // ---- online softmax: per nf, 16 in-lane vals + xor16/xor32 ----
        float alpha_s[2];
#pragma unroll
        for (int nf = 0; nf < 2; ++nf) {
            float mx = s[0][nf][0];
#pragma unroll
            for (int mf = 0; mf < 4; ++mf)
#pragma unroll
                for (int r = 0; r < 4; ++r) mx = fmaxf(mx, s[mf][nf][r]);
            mx = fmaxf(mx, __shfl_xor(mx, 16));
            mx = fmaxf(mx, __shfl_xor(mx, 32));
            const float mnew = fmaxf(mrow[nf], mx);
            const float a = __expf(mrow[nf] - mnew);
            float sum = 0.f;
#pragma unroll
            for (int mf = 0; mf < 4; ++mf)
#pragma unroll
                for (int r = 0; r < 4; ++r) {
                    const float p = __expf(s[mf][nf][r] - mnew);
                    s[mf][nf][r] = p;
                    sum += p;
                }
            sum += __shfl_xor(sum, 16);
            sum += __shfl_xor(sum, 32);
            lrow[nf] = lrow[nf] * a + sum;
            mrow[nf] = mnew;
            alpha_s[nf] = a;
        }

        // ---- rescale O by alpha (alpha lives at q=lane&15; O rows at g*4+r) ----
#pragma unroll
        for (int qm = 0; qm < 2; ++qm) {
#pragma unroll
            for (int r = 0; r < 4; ++r) {
                const float ao = __shfl(alpha_s[qm], (g << 2) | r);
#pragma unroll
                for (int dn = 0; dn < 5; ++dn) o[qm][dn][r] *= ao;
            }
        }

        // ---- pack P to bf16 pairs ----
        int pk[4][2][2];
#pragma unroll
        for (int mf = 0; mf < 4; ++mf)
#pragma unroll
            for (int nf = 0; nf < 2; ++nf) {
                pk[mf][nf][0] = packp(s[mf][nf][0], s[mf][nf][1]);
                pk[mf][nf][1] = packp(s[mf][nf][2], s[mf][nf][3]);
            }

        // ---- redistribute P to PV A-fragments ----
        // dest lane g needs kv = ks2*32 + g*8 + i; source (mf = 2*ks2 + (g>>1),
        // srcLane = lq + 32*(g&1) + 16*(j>>1), half = j&1)
        bf16x8 pfrag[2][2];
#pragma unroll
        for (int qm = 0; qm < 2; ++qm) {
#pragma unroll
            for (int ks2 = 0; ks2 < 2; ++ks2) {
                union { int w[4]; bf16x8 v; } pw;
#pragma unroll
                for (int j = 0; j < 4; ++j) {
                    const int srcLane = lq + 32 * ((lane >> 4) & 1) + 16 * (j >> 1);
                    const int vA = __shfl(pk[2 * ks2 + 0][qm][j & 1], srcLane);
                    const int vB = __shfl(pk[2 * ks2 + 1][qm][j & 1], srcLane);
                    pw.w[j] = (lane >> 5) ? vB : vA;
                }
                pfrag[qm][ks2] = pw.v;
            }
        }

        // ---- PV: O += P @ V ----
#pragma unroll
        for (int ks2 = 0; ks2 < 2; ++ks2) {
#pragma unroll
            for (int dn = 0; dn < 5; ++dn) {
                bf16x8 vb = *(const bf16x8*)&Vt[dn * 16 + lq][ks2 * 32 + g * 8];
#pragma unroll
                for (int qm = 0; qm < 2; ++qm)
                    o[qm][dn] = MFMA16(pfrag[qm][ks2], vb, o[qm][dn]);
            }
        }
    }

    // ---- epilogue: divide by l (shuffled to O's row layout), write out ----
#pragma unroll
    for (int qm = 0; qm < 2; ++qm) {
        const float invl = 1.0f / lrow[qm];
#pragma unroll
        for (int r = 0; r < 4; ++r) {
            const float iv = __shfl(invl, (g << 2) | r);
            const int row = qb + wq * 32 + qm * 16 + g * 4 + r;
#pragma unroll
            for (int dn = 0; dn < 5; ++dn)
                o_out[(size_t)row * DIM + h * HD + dn * 16 + lq] = o[qm][dn][r] * iv;
        }
    }
}

// ---------------------------------------------------------------------------
extern "C" void kernel_launch(void* const* d_in, const int* in_sizes, int n_in,
                              void* d_out, int out_size, void* d_ws, size_t ws_size,
                              hipStream_t stream)
{
    const float* hidden = (const float*)d_in[0];
    const float* cos_t  = (const float*)d_in[2];
    const float* sin_t  = (const float*)d_in[3];
    const float* qkv_w  = (const float*)d_in[4];
    const float* qkv_b  = (const float*)d_in[5];
    const float* proj_w = (const float*)d_in[6];
    const float* proj_b = (const float*)d_in[7];
    float* out = (float*)d_out;

    float* ws  = (float*)d_ws;
    float* qkv = ws;                                          // [3][NH][SEQ][HD] fp32
    float* qf  = qkv;
    float* kf  = qkv + (size_t)NH * SEQ * HD;
    float* vf  = qkv + (size_t)2 * NH * SEQ * HD;
    unsigned short* vth = (unsigned short*)(ws + (size_t)3 * NH * SEQ * HD); // [NH][HD][SEQ] bf16
    float* attnbuf = vf;   // alias: v fp32 is dead after vtrans

    gemm_kernel<true><<<dim3(N3 / 128, SEQ / 128), 256, 0, stream>>>(
        hidden, qkv_w, qkv_b, qkv);

    rope_kernel<<<(2 * NH * SEQ * 40 + 255) / 256, 256, 0, stream>>>(
        qkv, cos_t, sin_t);

    vtrans_kernel<<<dim3(SEQ / 64, NH), 256, 0, stream>>>(vf, vth);

    attn_mfma<<<dim3(SEQ / 128, NH), 256, 0, stream>>>(qf, kf, vth, attnbuf);

    gemm_kernel<false><<<dim3(DIM / 128, SEQ / 128), 256, 0, stream>>>(
        attnbuf, proj_w, proj_b, out);
}

// Round 3
// 909.855 us; speedup vs baseline: 2.4233x; 1.1004x over previous
//
#include <hip/hip_runtime.h>

#define SEQ   4096
#define NH    16
#define HD    80
#define DIM   1280
#define N3    3840
#define KDIM  1280
#define SCALE 0.11180339887498949f   // 80^-0.5

typedef __bf16 bf16x8 __attribute__((ext_vector_type(8)));
typedef float  f32x4  __attribute__((ext_vector_type(4)));

#define MFMA16(A,B,C) __builtin_amdgcn_mfma_f32_16x16x32_bf16(A,B,C,0,0,0)

static __device__ __forceinline__ unsigned short f2bf(float x){
    unsigned int u = __builtin_bit_cast(unsigned int, x);
    u = (u + 0x7FFFu + ((u >> 16) & 1u)) >> 16;   // RTNE, finite inputs
    return (unsigned short)u;
}
static __device__ __forceinline__ float bf2f(unsigned short h){
    return __builtin_bit_cast(float, ((unsigned int)h) << 16);
}
static __device__ __forceinline__ int packp(float a, float b){
    return (int)f2bf(a) | ((int)f2bf(b) << 16);
}

// ---------------------------------------------------------------------------
// fp32 -> bf16 hi/lo plane split (memory-bound, float4 vectorized)
// ---------------------------------------------------------------------------
__global__ __launch_bounds__(256)
void split_kernel(const float* __restrict__ src, unsigned short* __restrict__ hi,
                  unsigned short* __restrict__ lo, int n4)
{
    for (int i = blockIdx.x * 256 + threadIdx.x; i < n4; i += gridDim.x * 256) {
        float4 x = ((const float4*)src)[i];
        float xs[4] = {x.x, x.y, x.z, x.w};
        unsigned int h[4], l[4];
#pragma unroll
        for (int j = 0; j < 4; ++j) {
            h[j] = f2bf(xs[j]);
            l[j] = f2bf(xs[j] - bf2f((unsigned short)h[j]));
        }
        uint2 hw, lw;
        hw.x = h[0] | (h[1] << 16); hw.y = h[2] | (h[3] << 16);
        lw.x = l[0] | (l[1] << 16); lw.y = l[2] | (l[3] << 16);
        ((uint2*)hi)[i] = hw;
        ((uint2*)lo)[i] = lw;
    }
}

// ---------------------------------------------------------------------------
// bf16 hi/lo split MFMA GEMM: C = A @ W^T + bias  (3-term: AHWH+AHWL+ALWH)
// A planes [M][1280] bf16, W planes [N][1280] bf16.
// 128x128 tile, 4 waves 2x2 (64x64 each), BK=64, reg-staged LDS.
// LDS row stride 72 elems (144 B = 36 banks == 4 mod 32): both the staging
// ds_write pattern (8 octets/row) and the 16-row fragment ds_read_b128
// sweep all 32 banks -> conflict-free.
// ---------------------------------------------------------------------------
template <bool SCATTER>
__global__ __launch_bounds__(256, 2)
void gemm_bf16(const unsigned short* __restrict__ Ahi, const unsigned short* __restrict__ Alo,
               const unsigned short* __restrict__ Bhi, const unsigned short* __restrict__ Blo,
               const float* __restrict__ bias, float* __restrict__ C)
{
    __shared__ unsigned short sAh[128][72];
    __shared__ unsigned short sAl[128][72];
    __shared__ unsigned short sBh[128][72];
    __shared__ unsigned short sBl[128][72];

    const int tid = threadIdx.x;
    const int lane = tid & 63;
    const int lq = lane & 15;
    const int g = lane >> 4;
    const int wave = tid >> 6;
    const int wr = wave >> 1;       // m-half
    const int wc = wave & 1;        // n-half
    const int bm = blockIdx.y * 128;
    const int bn = blockIdx.x * 128;

    int orow[4], ooc[4];
#pragma unroll
    for (int i = 0; i < 4; ++i) {
        const int o = tid + 256 * i;
        orow[i] = o >> 3;
        ooc[i] = (o & 7) * 8;       // elem col within BK=64
    }

    f32x4 acc[4][4];
#pragma unroll
    for (int i = 0; i < 4; ++i)
#pragma unroll
        for (int j = 0; j < 4; ++j) acc[i][j] = (f32x4)0.f;

    uint4 rAh[4], rAl[4], rBh[4], rBl[4];
#define LOADT(kb)                                                                  \
    do {                                                                           \
        _Pragma("unroll")                                                          \
        for (int i = 0; i < 4; ++i) {                                              \
            const size_t ao = (size_t)(bm + orow[i]) * KDIM + (kb) + ooc[i];       \
            const size_t bo = (size_t)(bn + orow[i]) * KDIM + (kb) + ooc[i];       \
            rAh[i] = *(const uint4*)&Ahi[ao];                                      \
            rAl[i] = *(const uint4*)&Alo[ao];                                      \
            rBh[i] = *(const uint4*)&Bhi[bo];                                      \
            rBl[i] = *(const uint4*)&Blo[bo];                                      \
        }                                                                          \
    } while (0)

    LOADT(0);
    for (int kb = 0; kb < KDIM; kb += 64) {
        __syncthreads();   // previous compute done reading LDS
#pragma unroll
        for (int i = 0; i < 4; ++i) {
            *(uint4*)&sAh[orow[i]][ooc[i]] = rAh[i];
            *(uint4*)&sAl[orow[i]][ooc[i]] = rAl[i];
            *(uint4*)&sBh[orow[i]][ooc[i]] = rBh[i];
            *(uint4*)&sBl[orow[i]][ooc[i]] = rBl[i];
        }
        __syncthreads();   // tile ready
        if (kb + 64 < KDIM) LOADT(kb + 64);   // prefetch overlaps compute

#pragma unroll
        for (int ks = 0; ks < 2; ++ks) {
            bf16x8 aH[4], aL[4], bH[4], bL[4];
#pragma unroll
            for (int mf = 0; mf < 4; ++mf) {
                aH[mf] = *(const bf16x8*)&sAh[wr * 64 + mf * 16 + lq][ks * 32 + g * 8];
                aL[mf] = *(const bf16x8*)&sAl[wr * 64 + mf * 16 + lq][ks * 32 + g * 8];
            }
#pragma unroll
            for (int nf = 0; nf < 4; ++nf) {
                bH[nf] = *(const bf16x8*)&sBh[wc * 64 + nf * 16 + lq][ks * 32 + g * 8];
                bL[nf] = *(const bf16x8*)&sBl[wc * 64 + nf * 16 + lq][ks * 32 + g * 8];
            }
#pragma unroll
            for (int mf = 0; mf < 4; ++mf)
#pragma unroll
                for (int nf = 0; nf < 4; ++nf) {
                    acc[mf][nf] = MFMA16(aH[mf], bH[nf], acc[mf][nf]);
                    acc[mf][nf] = MFMA16(aH[mf], bL[nf], acc[mf][nf]);
                    acc[mf][nf] = MFMA16(aL[mf], bH[nf], acc[mf][nf]);
                }
        }
    }
#undef LOADT

    // epilogue: D row = g*4+r (A's m), col = lq (W's n)
#pragma unroll
    for (int mf = 0; mf < 4; ++mf) {
        const int m = bm + wr * 64 + mf * 16 + g * 4;
#pragma unroll
        for (int nf = 0; nf < 4; ++nf) {
            const int n = bn + wc * 64 + nf * 16 + lq;
            const float bv = bias[n];
#pragma unroll
            for (int r = 0; r < 4; ++r) {
                const float v = acc[mf][nf][r] + bv;
                if (SCATTER) {
                    const int which = n / DIM;
                    const int rem = n - which * DIM;
                    const int hh = rem / HD;
                    const int d = rem - hh * HD;
                    C[((size_t)(which * NH + hh) * SEQ + (m + r)) * HD + d] = v;
                } else {
                    C[(size_t)(m + r) * DIM + n] = v;
                }
            }
        }
    }
}

// ---------------------------------------------------------------------------
// RoPE in-place on q,k; folds 80^-0.5 into q.
// ---------------------------------------------------------------------------
__global__ __launch_bounds__(256)
void rope_kernel(float* __restrict__ qkv, const float* __restrict__ cos_t,
                 const float* __restrict__ sin_t)
{
    const int idx = blockIdx.x * 256 + threadIdx.x;
    if (idx >= 2 * NH * SEQ * 40) return;
    const int d = idx % 40;
    const int s = (idx / 40) % SEQ;
    const int h = (idx / (40 * SEQ)) % NH;
    const int which = idx / (40 * SEQ * NH);
    float* base = qkv + ((size_t)(which * NH + h) * SEQ + s) * HD;
    const float x0 = base[d];
    const float x1 = base[d + 40];
    const float c0 = cos_t[s * HD + d];
    const float c1 = cos_t[s * HD + d + 40];
    const float s0 = sin_t[s * HD + d];
    const float s1 = sin_t[s * HD + d + 40];
    const float sc = (which == 0) ? SCALE : 1.0f;
    base[d]      = (x0 * c0 - x1 * s0) * sc;
    base[d + 40] = (x1 * c1 + x0 * s1) * sc;
}

// ---------------------------------------------------------------------------
// V transpose + bf16 convert: v[h][s][d] fp32 -> vt[h][d][s] bf16
// ---------------------------------------------------------------------------
__global__ __launch_bounds__(256)
void vtrans_kernel(const float* __restrict__ v, unsigned short* __restrict__ vt)
{
    __shared__ float tile[64][84];
    const int tid = threadIdx.x;
    const int h = blockIdx.y;
    const int s0 = blockIdx.x * 64;
    const float* vh = v + (size_t)h * SEQ * HD;
#pragma unroll
    for (int ii = 0; ii < 5; ++ii) {
        const int id = tid + 256 * ii;
        const int r = id / 20, c4 = (id % 20) * 4;
        *(float4*)&tile[r][c4] = *(const float4*)(vh + (size_t)(s0 + r) * HD + c4);
    }
    __syncthreads();
#pragma unroll
    for (int ii = 0; ii < 5; ++ii) {
        const int id = tid + 256 * ii;
        const int d = id >> 4, c = (id & 15) * 4;
        const unsigned int u0 = f2bf(tile[c + 0][d]);
        const unsigned int u1 = f2bf(tile[c + 1][d]);
        const unsigned int u2 = f2bf(tile[c + 2][d]);
        const unsigned int u3 = f2bf(tile[c + 3][d]);
        uint2 w; w.x = u0 | (u1 << 16); w.y = u2 | (u3 << 16);
        *(uint2*)(vt + ((size_t)h * HD + d) * SEQ + s0 + c) = w;
    }
}

// ---------------------------------------------------------------------------
// MFMA flash attention (unchanged from R1; see R1 notes for layout derivation)
// ---------------------------------------------------------------------------
__global__ __launch_bounds__(256, 2)
void attn_mfma(const float* __restrict__ q, const float* __restrict__ kk,
               const unsigned short* __restrict__ vt, float* __restrict__ o_out)
{
    __shared__ unsigned short Khi[64][104];
    __shared__ unsigned short Klo[64][104];
    __shared__ unsigned short Vt[80][72];

    const int tid = threadIdx.x;
    const int wq = tid >> 6;
    const int lane = tid & 63;
    const int lq = lane & 15;
    const int g = lane >> 4;
    const int h = blockIdx.y;
    const int qb = blockIdx.x * 128;

    const float* qh = q + (size_t)h * SEQ * HD;
    const float* kh = kk + (size_t)h * SEQ * HD;
    const unsigned short* vth = vt + (size_t)h * HD * SEQ;

    for (int i = tid; i < 64 * 24; i += 256) {
        const int r = i / 24, c = 80 + i % 24;
        Khi[r][c] = 0; Klo[r][c] = 0;
    }

    bf16x8 qhiF[2][3], qloF[2][3];
#pragma unroll
    for (int nf = 0; nf < 2; ++nf) {
        const int qr = qb + wq * 32 + nf * 16 + lq;
        const float* qp = qh + (size_t)qr * HD;
#pragma unroll
        for (int ks = 0; ks < 3; ++ks) {
            const int d0 = ks * 32 + g * 8;
            union { unsigned short u[8]; bf16x8 v; } uh, ul;
            if (d0 < 80) {
                float4 x0 = *(const float4*)(qp + d0);
                float4 x1 = *(const float4*)(qp + d0 + 4);
                float xs[8] = {x0.x, x0.y, x0.z, x0.w, x1.x, x1.y, x1.z, x1.w};
#pragma unroll
                for (int i = 0; i < 8; ++i) {
                    const unsigned short hb = f2bf(xs[i]);
                    uh.u[i] = hb;
                    ul.u[i] = f2bf(xs[i] - bf2f(hb));
                }
            } else {
#pragma unroll
                for (int i = 0; i < 8; ++i) { uh.u[i] = 0; ul.u[i] = 0; }
            }
            qhiF[nf][ks] = uh.v; qloF[nf][ks] = ul.v;
        }
    }

    f32x4 o[2][5];
#pragma unroll
    for (int a = 0; a < 2; ++a)
#pragma unroll
        for (int b = 0; b < 5; ++b) o[a][b] = (f32x4)0.f;
    float mrow[2] = {-1e30f, -1e30f};
    float lrow[2] = {0.f, 0.f};

    for (int kb = 0; kb < SEQ; kb += 64) {
        float4 kld[5]; uint2 vld[5];
        int kr_[5], kc_[5], vd_[5], vc_[5];
#pragma unroll
        for (int ii = 0; ii < 5; ++ii) {
            const int id = tid + 256 * ii;
            kr_[ii] = id / 20; kc_[ii] = (id % 20) * 4;
            kld[ii] = *(const float4*)(kh + (size_t)(kb + kr_[ii]) * HD + kc_[ii]);
        }
#pragma unroll
        for (int ii = 0; ii < 5; ++ii) {
            const int id = tid + 256 * ii;
            vd_[ii] = id >> 4; vc_[ii] = (id & 15) * 4;
            vld[ii] = *(const uint2*)(vth + (size_t)vd_[ii] * SEQ + kb + vc_[ii]);
        }
        __syncthreads();
#pragma unroll
        for (int ii = 0; ii < 5; ++ii) {
            float xs[4] = {kld[ii].x, kld[ii].y, kld[ii].z, kld[ii].w};
            unsigned int hs[4], ls[4];
#pragma unroll
            for (int j = 0; j < 4; ++j) {
                hs[j] = f2bf(xs[j]);
                ls[j] = f2bf(xs[j] - bf2f((unsigned short)hs[j]));
            }
            uint2 wh, wl;
            wh.x = hs[0] | (hs[1] << 16); wh.y = hs[2] | (hs[3] << 16);
            wl.x = ls[0] | (ls[1] << 16); wl.y = ls[2] | (ls[3] << 16);
            *(uint2*)&Khi[kr_[ii]][kc_[ii]] = wh;
            *(uint2*)&Klo[kr_[ii]][kc_[ii]] = wl;
        }
#pragma unroll
        for (int ii = 0; ii < 5; ++ii)
            *(uint2*)&Vt[vd_[ii]][vc_[ii]] = vld[ii];
        __syncthreads();

        f32x4 s[4][2];
#pragma unroll
        for (int mf = 0; mf < 4; ++mf)
#pragma unroll
            for (int nf = 0; nf < 2; ++nf) s[mf][nf] = (f32x4)0.f;
#pragma unroll
        for (int ks = 0; ks < 3; ++ks) {
#pragma unroll
            for (int mf = 0; mf < 4; ++mf) {
                bf16x8 ah = *(const bf16x8*)&Khi[mf * 16 + lq][ks * 32 + g * 8];
                bf16x8 al = *(const bf16x8*)&Klo[mf * 16 + lq][ks * 32 + g * 8];
#pragma unroll
                for (int nf = 0; nf < 2; ++nf) {
                    s[mf][nf] = MFMA16(ah, qhiF[nf][ks], s[mf][nf]);
                    s[mf][nf] = MFMA16(ah, qloF[nf][ks], s[mf][nf]);
                    s[mf][nf] = MFMA16(al, qhiF[nf][ks], s[mf][nf]);
                }
            }
        }

        float alpha_s[2];
#pragma unroll
        for (int nf = 0; nf < 2; ++nf) {
            float mx = s[0][nf][0];
#pragma unroll
            for (int mf = 0; mf < 4; ++mf)
#pragma unroll
                for (int r = 0; r < 4; ++r) mx = fmaxf(mx, s[mf][nf][r]);
            mx = fmaxf(mx, __shfl_xor(mx, 16));
            mx = fmaxf(mx, __shfl_xor(mx, 32));
            const float mnew = fmaxf(mrow[nf], mx);
            const float a = __expf(mrow[nf] - mnew);
            float sum = 0.f;
#pragma unroll
            for (int mf = 0; mf < 4; ++mf)
#pragma unroll
                for (int r = 0; r < 4; ++r) {
                    const float p = __expf(s[mf][nf][r] - mnew);
                    s[mf][nf][r] = p;
                    sum += p;
                }
            sum += __shfl_xor(sum, 16);
            sum += __shfl_xor(sum, 32);
            lrow[nf] = lrow[nf] * a + sum;
            mrow[nf] = mnew;
            alpha_s[nf] = a;
        }

#pragma unroll
        for (int qm = 0; qm < 2; ++qm) {
#pragma unroll
            for (int r = 0; r < 4; ++r) {
                const float ao = __shfl(alpha_s[qm], (g << 2) | r);
#pragma unroll
                for (int dn = 0; dn < 5; ++dn) o[qm][dn][r] *= ao;
            }
        }

        int pk[4][2][2];
#pragma unroll
        for (int mf = 0; mf < 4; ++mf)
#pragma unroll
            for (int nf = 0; nf < 2; ++nf) {
                pk[mf][nf][0] = packp(s[mf][nf][0], s[mf][nf][1]);
                pk[mf][nf][1] = packp(s[mf][nf][2], s[mf][nf][3]);
            }

        bf16x8 pfrag[2][2];
#pragma unroll
        for (int qm = 0; qm < 2; ++qm) {
#pragma unroll
            for (int ks2 = 0; ks2 < 2; ++ks2) {
                union { int w[4]; bf16x8 v; } pw;
#pragma unroll
                for (int j = 0; j < 4; ++j) {
                    const int srcLane = lq + 32 * ((lane >> 4) & 1) + 16 * (j >> 1);
                    const int vA = __shfl(pk[2 * ks2 + 0][qm][j & 1], srcLane);
                    const int vB = __shfl(pk[2 * ks2 + 1][qm][j & 1], srcLane);
                    pw.w[j] = (lane >> 5) ? vB : vA;
                }
                pfrag[qm][ks2] = pw.v;
            }
        }

#pragma unroll
        for (int ks2 = 0; ks2 < 2; ++ks2) {
#pragma unroll
            for (int dn = 0; dn < 5; ++dn) {
                bf16x8 vb = *(const bf16x8*)&Vt[dn * 16 + lq][ks2 * 32 + g * 8];
#pragma unroll
                for (int qm = 0; qm < 2; ++qm)
                    o[qm][dn] = MFMA16(pfrag[qm][ks2], vb, o[qm][dn]);
            }
        }
    }

#pragma unroll
    for (int qm = 0; qm < 2; ++qm) {
        const float invl = 1.0f / lrow[qm];
#pragma unroll
        for (int r = 0; r < 4; ++r) {
            const float iv = __shfl(invl, (g << 2) | r);
            const int row = qb + wq * 32 + qm * 16 + g * 4 + r;
#pragma unroll
            for (int dn = 0; dn < 5; ++dn)
                o_out[(size_t)row * DIM + h * HD + dn * 16 + lq] = o[qm][dn][r] * iv;
        }
    }
}

// ---------------------------------------------------------------------------
extern "C" void kernel_launch(void* const* d_in, const int* in_sizes, int n_in,
                              void* d_out, int out_size, void* d_ws, size_t ws_size,
                              hipStream_t stream)
{
    const float* hidden = (const float*)d_in[0];
    const float* cos_t  = (const float*)d_in[2];
    const float* sin_t  = (const float*)d_in[3];
    const float* qkv_w  = (const float*)d_in[4];
    const float* qkv_b  = (const float*)d_in[5];
    const float* proj_w = (const float*)d_in[6];
    const float* proj_b = (const float*)d_in[7];
    float* out = (float*)d_out;

    char* ws = (char*)d_ws;
    // [0, 62.9MB): qkv fp32 [3][NH][SEQ][HD]
    float* qkv = (float*)ws;
    float* qf  = qkv;
    float* kf  = qkv + (size_t)NH * SEQ * HD;       // +20,971,520 B
    float* vf  = qkv + (size_t)2 * NH * SEQ * HD;   // +41,943,040 B
    // [62.9MB, 103.5MB): hidden + qkv_w hi/lo splits (live only through QKV gemm)
    unsigned short* hHi = (unsigned short*)(ws + 62914560);
    unsigned short* hLo = hHi + (size_t)SEQ * DIM;          // 5,242,880 elems
    unsigned short* wHi = hLo + (size_t)SEQ * DIM;
    unsigned short* wLo = wHi + (size_t)N3 * DIM;           // 4,915,200 elems
    // aliases (regions dead by the time these are written):
    unsigned short* vth = (unsigned short*)(ws + 62914560); // over hHi/hLo
    unsigned short* aHi = (unsigned short*)ws;              // over qf
    unsigned short* aLo = aHi + (size_t)SEQ * DIM;
    unsigned short* pHi = (unsigned short*)(ws + 20971520); // over kf
    unsigned short* pLo = pHi + (size_t)DIM * DIM;
    float* attnbuf = vf;

    split_kernel<<<2048, 256, 0, stream>>>(hidden, hHi, hLo, SEQ * DIM / 4);
    split_kernel<<<2048, 256, 0, stream>>>(qkv_w, wHi, wLo, N3 * DIM / 4);

    gemm_bf16<true><<<dim3(N3 / 128, SEQ / 128), 256, 0, stream>>>(
        hHi, hLo, wHi, wLo, qkv_b, qkv);

    rope_kernel<<<(2 * NH * SEQ * 40 + 255) / 256, 256, 0, stream>>>(
        qkv, cos_t, sin_t);

    vtrans_kernel<<<dim3(SEQ / 64, NH), 256, 0, stream>>>(vf, vth);

    attn_mfma<<<dim3(SEQ / 128, NH), 256, 0, stream>>>(qf, kf, vth, attnbuf);

    split_kernel<<<2048, 256, 0, stream>>>(attnbuf, aHi, aLo, SEQ * DIM / 4);
    split_kernel<<<1024, 256, 0, stream>>>(proj_w, pHi, pLo, DIM * DIM / 4);

    gemm_bf16<false><<<dim3(DIM / 128, SEQ / 128), 256, 0, stream>>>(
        aHi, aLo, pHi, pLo, proj_b, out);
}